// Round 1
// baseline (2642.844 us; speedup 1.0000x reference)
//
#include <hip/hip_runtime.h>
#include <cstdint>

typedef unsigned short u16;
typedef unsigned int u32;
typedef __attribute__((ext_vector_type(8))) u16 ushort8v;

#define CH 384
#define NPIX 16384
#define NB 8

static __device__ __forceinline__ float bf2f(u16 u) {
  return __uint_as_float(((u32)u) << 16);
}
static __device__ __forceinline__ u16 f2bf(float f) {
  u32 x = __float_as_uint(f);
  u32 r = (x + 0x7fffu + ((x >> 16) & 1u)) >> 16;
  return (u16)r;
}

// ---------------------------------------------------------------------------
// GEMM1: P[b][m][p] = sum_k W[m][k] * X[b][k][p] + bias[m], output bf16.
// 128x128 tile, 256 threads, 8x8 acc/thread, K-step 16. fp32 VALU (round 1).
// ---------------------------------------------------------------------------
__global__ __launch_bounds__(256) void gemm_pw(
    const float* __restrict__ X, const float* __restrict__ W,
    const float* __restrict__ bias, u16* __restrict__ P) {
  __shared__ float As[16][136];  // transposed: As[k][m], pad 136 (16B-aligned rows)
  __shared__ float Bs[16][136];
  const int t = threadIdx.x;
  const int tx = t & 15, ty = t >> 4;
  const int m0 = blockIdx.y * 128, p0 = blockIdx.x * 128;
  const int b = blockIdx.z;
  const float* Xb = X + (size_t)b * CH * NPIX;
  float acc[8][8];
#pragma unroll
  for (int i = 0; i < 8; ++i)
#pragma unroll
    for (int j = 0; j < 8; ++j) acc[i][j] = 0.f;

  const int r = t >> 1, half = t & 1;
  for (int k0 = 0; k0 < CH; k0 += 16) {
    {
      const float* src = W + (size_t)(m0 + r) * CH + k0 + half * 8;
      float4 a0 = *(const float4*)src;
      float4 a1 = *(const float4*)(src + 4);
      const int kk = half * 8;
      As[kk + 0][r] = a0.x; As[kk + 1][r] = a0.y;
      As[kk + 2][r] = a0.z; As[kk + 3][r] = a0.w;
      As[kk + 4][r] = a1.x; As[kk + 5][r] = a1.y;
      As[kk + 6][r] = a1.z; As[kk + 7][r] = a1.w;
    }
    {
      const int row = t >> 4, c8 = (t & 15) * 8;
      const float* src = Xb + (size_t)(k0 + row) * NPIX + p0 + c8;
      *(float4*)&Bs[row][c8] = *(const float4*)src;
      *(float4*)&Bs[row][c8 + 4] = *(const float4*)(src + 4);
    }
    __syncthreads();
#pragma unroll
    for (int kk = 0; kk < 16; ++kk) {
      float4 a0 = *(float4*)&As[kk][ty * 8];
      float4 a1 = *(float4*)&As[kk][ty * 8 + 4];
      float4 b0 = *(float4*)&Bs[kk][tx * 8];
      float4 b1 = *(float4*)&Bs[kk][tx * 8 + 4];
      float av[8] = {a0.x, a0.y, a0.z, a0.w, a1.x, a1.y, a1.z, a1.w};
      float bv[8] = {b0.x, b0.y, b0.z, b0.w, b1.x, b1.y, b1.z, b1.w};
#pragma unroll
      for (int i = 0; i < 8; ++i)
#pragma unroll
        for (int j = 0; j < 8; ++j) acc[i][j] = fmaf(av[i], bv[j], acc[i][j]);
    }
    __syncthreads();
  }
#pragma unroll
  for (int i = 0; i < 8; ++i) {
    const int row = m0 + ty * 8 + i;
    const float bb = bias[row];
    ushort8v sv;
#pragma unroll
    for (int j = 0; j < 8; ++j) sv[j] = f2bf(acc[i][j] + bb);
    *(ushort8v*)(P + ((size_t)b * CH + row) * NPIX + p0 + tx * 8) = sv;
  }
}

// ---------------------------------------------------------------------------
// GEMM2: Out[b][o][p] = sum_k M2[b][o][k] * V[b][k][p] + prj_b[o], fp32 out.
// ---------------------------------------------------------------------------
__global__ __launch_bounds__(256) void gemm_out_k(
    const float* __restrict__ M2, const u16* __restrict__ V,
    const float* __restrict__ prj_b, float* __restrict__ Out) {
  __shared__ float As[16][136];
  __shared__ float Bs[16][136];
  const int t = threadIdx.x;
  const int tx = t & 15, ty = t >> 4;
  const int m0 = blockIdx.y * 128, p0 = blockIdx.x * 128;
  const int b = blockIdx.z;
  const float* Ab = M2 + (size_t)b * CH * CH;
  const u16* Vb = V + (size_t)b * CH * NPIX;
  float acc[8][8];
#pragma unroll
  for (int i = 0; i < 8; ++i)
#pragma unroll
    for (int j = 0; j < 8; ++j) acc[i][j] = 0.f;

  const int r = t >> 1, half = t & 1;
  for (int k0 = 0; k0 < CH; k0 += 16) {
    {
      const float* src = Ab + (size_t)(m0 + r) * CH + k0 + half * 8;
      float4 a0 = *(const float4*)src;
      float4 a1 = *(const float4*)(src + 4);
      const int kk = half * 8;
      As[kk + 0][r] = a0.x; As[kk + 1][r] = a0.y;
      As[kk + 2][r] = a0.z; As[kk + 3][r] = a0.w;
      As[kk + 4][r] = a1.x; As[kk + 5][r] = a1.y;
      As[kk + 6][r] = a1.z; As[kk + 7][r] = a1.w;
    }
    {
      const int row = t >> 4, c8 = (t & 15) * 8;
      ushort8v bv8 = *(const ushort8v*)(Vb + (size_t)(k0 + row) * NPIX + p0 + c8);
      float4 f0, f1;
      f0.x = bf2f(bv8[0]); f0.y = bf2f(bv8[1]); f0.z = bf2f(bv8[2]); f0.w = bf2f(bv8[3]);
      f1.x = bf2f(bv8[4]); f1.y = bf2f(bv8[5]); f1.z = bf2f(bv8[6]); f1.w = bf2f(bv8[7]);
      *(float4*)&Bs[row][c8] = f0;
      *(float4*)&Bs[row][c8 + 4] = f1;
    }
    __syncthreads();
#pragma unroll
    for (int kk = 0; kk < 16; ++kk) {
      float4 a0 = *(float4*)&As[kk][ty * 8];
      float4 a1 = *(float4*)&As[kk][ty * 8 + 4];
      float4 b0 = *(float4*)&Bs[kk][tx * 8];
      float4 b1 = *(float4*)&Bs[kk][tx * 8 + 4];
      float av[8] = {a0.x, a0.y, a0.z, a0.w, a1.x, a1.y, a1.z, a1.w};
      float bv[8] = {b0.x, b0.y, b0.z, b0.w, b1.x, b1.y, b1.z, b1.w};
#pragma unroll
      for (int i = 0; i < 8; ++i)
#pragma unroll
        for (int j = 0; j < 8; ++j) acc[i][j] = fmaf(av[i], bv[j], acc[i][j]);
    }
    __syncthreads();
  }
#pragma unroll
  for (int i = 0; i < 8; ++i) {
    const int row = m0 + ty * 8 + i;
    const float bb = prj_b[row];
    float4 o0 = make_float4(acc[i][0] + bb, acc[i][1] + bb, acc[i][2] + bb, acc[i][3] + bb);
    float4 o1 = make_float4(acc[i][4] + bb, acc[i][5] + bb, acc[i][6] + bb, acc[i][7] + bb);
    float* dst = Out + ((size_t)b * CH + row) * NPIX + p0 + tx * 8;
    *(float4*)dst = o0;
    *(float4*)(dst + 4) = o1;
  }
}

// ---------------------------------------------------------------------------
// Depthwise 3x3, SAME zero padding, bf16 in/out (fp32 accumulate).
// Block: 32x32 pixel tile (2x2 px/thread), grid (4,4, NB*CH).
// ---------------------------------------------------------------------------
__global__ __launch_bounds__(256) void dwconv(
    const u16* __restrict__ Pin, const float* __restrict__ Wd,
    const float* __restrict__ bd, u16* __restrict__ Outp) {
  __shared__ u16 s[34][40];
  const int t = threadIdx.x;
  const int bc = blockIdx.z;
  const int c = bc % CH;
  const u16* pin = Pin + (size_t)bc * NPIX;
  u16* pout = Outp + (size_t)bc * NPIX;
  float w[9];
#pragma unroll
  for (int i = 0; i < 9; ++i) w[i] = Wd[c * 9 + i];
  const float bb = bd[c];
  const int y0 = blockIdx.y * 32, x0 = blockIdx.x * 32;
  for (int idx = t; idx < 34 * 34; idx += 256) {
    const int hy = idx / 34, hx = idx - hy * 34;
    const int gy = y0 + hy - 1, gx = x0 + hx - 1;
    u16 v = 0;
    if (gy >= 0 && gy < 128 && gx >= 0 && gx < 128) v = pin[gy * 128 + gx];
    s[hy][hx] = v;
  }
  __syncthreads();
  const int py = (t >> 4) * 2, px = (t & 15) * 2;
#pragma unroll
  for (int dy = 0; dy < 2; ++dy)
#pragma unroll
    for (int dx = 0; dx < 2; ++dx) {
      const int oy = py + dy, ox = px + dx;
      float acc = bb;
#pragma unroll
      for (int i = 0; i < 3; ++i)
#pragma unroll
        for (int j = 0; j < 3; ++j)
          acc = fmaf(bf2f(s[oy + i][ox + j]), w[i * 3 + j], acc);
      pout[(y0 + oy) * 128 + x0 + ox] = f2bf(acc);
    }
}

// ---------------------------------------------------------------------------
// Gram: per (b,h): G[c][d] += sum_n q[c][n]*k[d][n]; SQ[c] += q^2; SK[d] += k^2.
// Grid (32 chunks of 512 px, 64 bh). Block = 64 threads, 6x6 cells each.
// ---------------------------------------------------------------------------
__global__ __launch_bounds__(64) void gram48(
    const u16* __restrict__ Q, const u16* __restrict__ Kt,
    float* __restrict__ G, float* __restrict__ SQ, float* __restrict__ SK) {
  __shared__ u16 qs[48][72];
  __shared__ u16 ks[48][72];
  const int t = threadIdx.x;
  const int tc = t >> 3, td = t & 7;
  const int chunk = blockIdx.x, bh = blockIdx.y;
  const size_t base = ((size_t)(bh >> 3) * CH + (bh & 7) * 48) * NPIX + (size_t)chunk * 512;
  float acc[6][6];
#pragma unroll
  for (int i = 0; i < 6; ++i)
#pragma unroll
    for (int j = 0; j < 6; ++j) acc[i][j] = 0.f;
  float sq6[6] = {0, 0, 0, 0, 0, 0}, sk6[6] = {0, 0, 0, 0, 0, 0};

  for (int it = 0; it < 8; ++it) {
    for (int idx = t; idx < 384; idx += 64) {
      const int row = idx >> 3, seg = idx & 7;
      const size_t off = base + (size_t)row * NPIX + it * 64 + seg * 8;
      *(ushort8v*)&qs[row][seg * 8] = *(const ushort8v*)(Q + off);
      *(ushort8v*)&ks[row][seg * 8] = *(const ushort8v*)(Kt + off);
    }
    __syncthreads();
    for (int pp = 0; pp < 32; ++pp) {
      float2 qf[6], kf[6];
#pragma unroll
      for (int i = 0; i < 6; ++i) {
        const u32 qu = *(const u32*)&qs[tc * 6 + i][pp * 2];
        const u32 ku = *(const u32*)&ks[td * 6 + i][pp * 2];
        qf[i].x = __uint_as_float(qu << 16);
        qf[i].y = __uint_as_float(qu & 0xffff0000u);
        kf[i].x = __uint_as_float(ku << 16);
        kf[i].y = __uint_as_float(ku & 0xffff0000u);
      }
#pragma unroll
      for (int i = 0; i < 6; ++i)
#pragma unroll
        for (int j = 0; j < 6; ++j) {
          acc[i][j] = fmaf(qf[i].x, kf[j].x, acc[i][j]);
          acc[i][j] = fmaf(qf[i].y, kf[j].y, acc[i][j]);
        }
      if (td == 0)
#pragma unroll
        for (int i = 0; i < 6; ++i) sq6[i] += qf[i].x * qf[i].x + qf[i].y * qf[i].y;
      if (tc == 0)
#pragma unroll
        for (int j = 0; j < 6; ++j) sk6[j] += kf[j].x * kf[j].x + kf[j].y * kf[j].y;
    }
    __syncthreads();
  }
#pragma unroll
  for (int i = 0; i < 6; ++i)
#pragma unroll
    for (int j = 0; j < 6; ++j)
      atomicAdd(&G[((size_t)bh * 48 + tc * 6 + i) * 48 + td * 6 + j], acc[i][j]);
  if (td == 0)
#pragma unroll
    for (int i = 0; i < 6; ++i) atomicAdd(&SQ[bh * 48 + tc * 6 + i], sq6[i]);
  if (tc == 0)
#pragma unroll
    for (int j = 0; j < 6; ++j) atomicAdd(&SK[bh * 48 + td * 6 + j], sk6[j]);
}

// ---------------------------------------------------------------------------
// Attention + fold projection: per (b,h) compute A = softmax(...), then
// M2[b][o][h*48+d] = sum_c prj_w[o][h*48+c] * A[c][d].  Grid (8 o-chunks, 64 bh).
// ---------------------------------------------------------------------------
__global__ __launch_bounds__(256) void attn_m2(
    const float* __restrict__ G, const float* __restrict__ SQ,
    const float* __restrict__ SK, const float* __restrict__ temp,
    const float* __restrict__ dc, const float* __restrict__ dl,
    const float* __restrict__ dp_w1, const float* __restrict__ dp_b1,
    const float* __restrict__ dp_w2, const float* __restrict__ dp_b2,
    const float* __restrict__ prj_w, float* __restrict__ M2) {
  __shared__ float hid[48];
  __shared__ float Ard[48][49];
  __shared__ float pw_s[48][49];
  const int t = threadIdx.x;
  const int oc = blockIdx.x;  // 0..7 -> output rows oc*48..+47
  const int bh = blockIdx.y;
  const int b = bh >> 3, h = bh & 7, h0 = h * 48;
  if (t < 48) {
    float s = dp_b1[t];
#pragma unroll
    for (int i = 0; i < 3; ++i) s += dc[b * 3 + i] * dp_w1[i * 48 + t];
    const float x3 = s * s * s;
    hid[t] = 0.5f * s * (1.f + tanhf(0.79788456080286536f * (s + 0.044715f * x3)));
  }
  for (int idx = t; idx < 48 * 48; idx += 256) {
    const int o = idx / 48, c2 = idx - o * 48;
    pw_s[o][c2] = prj_w[(size_t)(oc * 48 + o) * CH + h0 + c2];
  }
  __syncthreads();
  if (t < 48) {
    const int c = t;
    float dcp = dp_b2[h0 + c];
#pragma unroll
    for (int j = 0; j < 48; ++j) dcp += hid[j] * dp_w2[j * CH + h0 + c];
    const float rq = 1.f / fmaxf(sqrtf(SQ[bh * 48 + c]), 1e-12f);
    const float rowscale = temp[h] * dcp * dl[b] * rq;
    float vals[48];
    float m = -1e30f;
#pragma unroll
    for (int d = 0; d < 48; ++d) {
      const float rk = 1.f / fmaxf(sqrtf(SK[bh * 48 + d]), 1e-12f);
      const float v = G[((size_t)bh * 48 + c) * 48 + d] * rk * rowscale;
      vals[d] = v;
      m = fmaxf(m, v);
    }
    float ssum = 0.f;
#pragma unroll
    for (int d = 0; d < 48; ++d) {
      const float e = expf(vals[d] - m);
      vals[d] = e;
      ssum += e;
    }
    const float inv = 1.f / ssum;
#pragma unroll
    for (int d = 0; d < 48; ++d) Ard[c][d] = vals[d] * inv;
  }
  __syncthreads();
#pragma unroll
  for (int rIt = 0; rIt < 9; ++rIt) {
    const int idx = t + 256 * rIt;  // < 2304
    const int o = idx / 48, dd = idx - o * 48;
    float a = 0.f;
#pragma unroll
    for (int c2 = 0; c2 < 48; ++c2) a = fmaf(pw_s[o][c2], Ard[c2][dd], a);
    M2[((size_t)b * CH + oc * 48 + o) * CH + h0 + dd] = a;
  }
}

__global__ void zero_f32(float* __restrict__ p, int n) {
  const int i = blockIdx.x * blockDim.x + threadIdx.x;
  if (i < n) p[i] = 0.f;
}

// ---------------------------------------------------------------------------
// Workspace layout (bytes): A,Bq,Cw bf16 ping-pong buffers 3*100.66MB, then
// G (64*48*48 f32), SQ (64*48), SK (64*48), M2 (8*384*384 f32). Peak ~307 MB.
// ---------------------------------------------------------------------------
extern "C" void kernel_launch(void* const* d_in, const int* in_sizes, int n_in,
                              void* d_out, int out_size, void* d_ws, size_t ws_size,
                              hipStream_t stream) {
  (void)in_sizes; (void)n_in; (void)out_size; (void)ws_size;
  const float* x      = (const float*)d_in[0];
  const float* dc     = (const float*)d_in[1];
  const float* dl     = (const float*)d_in[2];
  const float* temp   = (const float*)d_in[3];
  const float* prj_w  = (const float*)d_in[4];
  const float* prj_b  = (const float*)d_in[5];
  const float* dp_w1  = (const float*)d_in[6];
  const float* dp_b1  = (const float*)d_in[7];
  const float* dp_w2  = (const float*)d_in[8];
  const float* dp_b2  = (const float*)d_in[9];
  const float* wq_pw  = (const float*)d_in[10];
  const float* wq_pwb = (const float*)d_in[11];
  const float* wq_dw  = (const float*)d_in[12];
  const float* wq_dwb = (const float*)d_in[13];
  const float* wk_pw  = (const float*)d_in[14];
  const float* wk_pwb = (const float*)d_in[15];
  const float* wk_dw  = (const float*)d_in[16];
  const float* wk_dwb = (const float*)d_in[17];
  const float* wv_pw  = (const float*)d_in[18];
  const float* wv_pwb = (const float*)d_in[19];
  const float* wv_dw  = (const float*)d_in[20];
  const float* wv_dwb = (const float*)d_in[21];

  const size_t TEN = (size_t)NB * CH * NPIX;  // elems per tensor
  u16* A  = (u16*)d_ws;
  u16* Bq = A + TEN;
  u16* Cw = Bq + TEN;
  float* G  = (float*)(Cw + TEN);
  float* SQ = G + 64 * 48 * 48;
  float* SK = SQ + 64 * 48;
  float* M2 = SK + 64 * 48;
  float* out = (float*)d_out;

  const dim3 gGemm(128, 3, NB);
  const dim3 gDw(4, 4, NB * CH);

  // q path: pw -> A, dw -> Bq (q)
  gemm_pw<<<gGemm, 256, 0, stream>>>(x, wq_pw, wq_pwb, A);
  dwconv<<<gDw, 256, 0, stream>>>(A, wq_dw, wq_dwb, Bq);
  // k path: pw -> A (P_q dead), dw -> Cw (k)
  gemm_pw<<<gGemm, 256, 0, stream>>>(x, wk_pw, wk_pwb, A);
  dwconv<<<gDw, 256, 0, stream>>>(A, wk_dw, wk_dwb, Cw);
  // gram + norms (ws is poisoned 0xAA -> zero first)
  zero_f32<<<dim3((64 * 48 * 48 + 2 * 64 * 48 + 255) / 256), 256, 0, stream>>>(
      G, 64 * 48 * 48 + 2 * 64 * 48);
  gram48<<<dim3(32, 64), 64, 0, stream>>>(Bq, Cw, G, SQ, SK);
  // v path: pw -> A, dw -> Bq (q dead; v into Bq)
  gemm_pw<<<gGemm, 256, 0, stream>>>(x, wv_pw, wv_pwb, A);
  dwconv<<<gDw, 256, 0, stream>>>(A, wv_dw, wv_dwb, Bq);
  // attention + fold prj -> M2
  attn_m2<<<dim3(8, 64), 256, 0, stream>>>(G, SQ, SK, temp, dc, dl,
                                           dp_w1, dp_b1, dp_w2, dp_b2, prj_w, M2);
  // final GEMM: out = M2 * v + prj_b
  gemm_out_k<<<gGemm, 256, 0, stream>>>(M2, Bq, prj_b, out);
}

// Round 2
// 1325.376 us; speedup vs baseline: 1.9940x; 1.9940x over previous
//
#include <hip/hip_runtime.h>
#include <cstdint>

typedef unsigned short u16;
typedef unsigned int u32;
typedef __attribute__((ext_vector_type(8))) u16 ushort8v;
typedef __attribute__((ext_vector_type(4))) u16 u16x4;
typedef __attribute__((ext_vector_type(8))) short short8;
typedef __attribute__((ext_vector_type(4))) float f32x4;

#define CH 384
#define NPIX 16384
#define NB 8

static __device__ __forceinline__ float bf2f(u16 u) {
  return __uint_as_float(((u32)u) << 16);
}
static __device__ __forceinline__ u16 f2bf(float f) {
  u32 x = __float_as_uint(f);
  u32 r = (x + 0x7fffu + ((x >> 16) & 1u)) >> 16;
  return (u16)r;
}

static __device__ __forceinline__ void gload16(const u16* g, u16* l) {
  __builtin_amdgcn_global_load_lds(
      (const __attribute__((address_space(1))) void*)(uintptr_t)g,
      (__attribute__((address_space(3))) void*)(uintptr_t)l, 16, 0, 0);
}

// ---------------------------------------------------------------------------
// Transpose+convert: X f32 [b][c][n] -> Xt bf16 [b][n][c]. 32x32 tiles.
// ---------------------------------------------------------------------------
__global__ __launch_bounds__(256) void transpose_x(
    const float* __restrict__ X, u16* __restrict__ Xt) {
  __shared__ u16 tile[32][33];
  const int t = threadIdx.x;
  const int b = blockIdx.z;
  const int n0 = blockIdx.x * 32, c0 = blockIdx.y * 32;
  {
    const int cr = t >> 3, n4 = (t & 7) * 4;
    float4 v = *(const float4*)(X + ((size_t)b * CH + c0 + cr) * NPIX + n0 + n4);
    tile[cr][n4 + 0] = f2bf(v.x);
    tile[cr][n4 + 1] = f2bf(v.y);
    tile[cr][n4 + 2] = f2bf(v.z);
    tile[cr][n4 + 3] = f2bf(v.w);
  }
  __syncthreads();
  {
    const int nr = t >> 3, c4 = (t & 7) * 4;
    u16x4 o;
    o.x = tile[c4 + 0][nr];
    o.y = tile[c4 + 1][nr];
    o.z = tile[c4 + 2][nr];
    o.w = tile[c4 + 3][nr];
    *(u16x4*)(Xt + ((size_t)b * NPIX + n0 + nr) * CH + c0 + c4) = o;
  }
}

// Convert the 3 pointwise weights (384x384 f32) to bf16, packed consecutively.
__global__ __launch_bounds__(256) void conv_w3(
    const float* __restrict__ a, const float* __restrict__ bsrc,
    const float* __restrict__ c, u16* __restrict__ dst) {
  const int i = blockIdx.x * 256 + threadIdx.x;
  if (i < CH * CH) {
    dst[i] = f2bf(a[i]);
    dst[CH * CH + i] = f2bf(bsrc[i]);
    dst[2 * CH * CH + i] = f2bf(c[i]);
  }
}

// ---------------------------------------------------------------------------
// MFMA GEMM, 128x128 tile, BK=32, 4 waves (2x2 of 64x64), 16x16x32 bf16.
// All operands bf16 stored [own-index][k] with k fast (row stride = CH).
// D[r][c]: r = A-row axis (reg-contiguous in output), c = B-col axis.
// MODE 0: r=n (A=Xt, batched), c=m (B=W, shared);  out bf16 P[m][n] (pixel-fast)
// MODE 1: r=m (A=W, shared),  c=n (B=Xt, batched); out bf16 Pt[n][m] (chan-fast)
// MODE 2: r=p (A=Vt, batched), c=o (B=M2, batched); out f32  out[o][p]
// ---------------------------------------------------------------------------
template <int MODE>
__global__ __launch_bounds__(256) void gemm_mfma(
    const u16* __restrict__ Aop, const u16* __restrict__ Bop,
    const float* __restrict__ bias, void* __restrict__ Outv) {
  __shared__ u16 sm[8192];  // A tile [128][32] @0, B tile [128][32] @4096
  const int t = threadIdx.x;
  const int lane = t & 63, w = t >> 6;
  const int b = blockIdx.z;
  const int r0 = blockIdx.x * 128, c0 = blockIdx.y * 128;

  const u16* Abase = (MODE == 1) ? (Aop + (size_t)r0 * CH)
                                 : (Aop + ((size_t)b * NPIX + r0) * CH);
  const u16* Bbase = (MODE == 0) ? (Bop + (size_t)c0 * CH)
                   : (MODE == 1) ? (Bop + ((size_t)b * NPIX + c0) * CH)
                                 : (Bop + ((size_t)b * CH + c0) * CH);

  const int wr = w >> 1, wc = w & 1;
  f32x4 acc[4][4] = {};
  const int srow = lane >> 2, scol = (lane & 3) * 8;
  const int fr = lane & 15, fg = lane >> 4;

  for (int k0 = 0; k0 < CH; k0 += 32) {
#pragma unroll
    for (int ii = 0; ii < 4; ++ii) {
      const int chunk = w * 4 + ii;  // 0..15
      const int c8 = chunk & 7;
      const u16* g = ((chunk < 8) ? Abase : Bbase) +
                     (size_t)(c8 * 16 + srow) * CH + k0 + scol;
      gload16(g, &sm[chunk * 512]);
    }
    __syncthreads();
    short8 a[4], bf[4];
#pragma unroll
    for (int rt = 0; rt < 4; ++rt)
      a[rt] = *(const short8*)&sm[(wr * 64 + rt * 16 + fr) * 32 + fg * 8];
#pragma unroll
    for (int ct = 0; ct < 4; ++ct)
      bf[ct] = *(const short8*)&sm[4096 + (wc * 64 + ct * 16 + fr) * 32 + fg * 8];
#pragma unroll
    for (int rt = 0; rt < 4; ++rt)
#pragma unroll
      for (int ct = 0; ct < 4; ++ct)
        acc[rt][ct] = __builtin_amdgcn_mfma_f32_16x16x32_bf16(
            a[rt], bf[ct], acc[rt][ct], 0, 0, 0);
    __syncthreads();
  }

#pragma unroll
  for (int rt = 0; rt < 4; ++rt) {
    const int row = r0 + wr * 64 + rt * 16 + fg * 4;  // + reg 0..3
#pragma unroll
    for (int ct = 0; ct < 4; ++ct) {
      const int col = c0 + wc * 64 + ct * 16 + fr;
      f32x4 v = acc[rt][ct];
      if (MODE == 0) {
        const float bb = bias[col];
        u16x4 o;
        o.x = f2bf(v[0] + bb); o.y = f2bf(v[1] + bb);
        o.z = f2bf(v[2] + bb); o.w = f2bf(v[3] + bb);
        *(u16x4*)((u16*)Outv + ((size_t)b * CH + col) * NPIX + row) = o;
      } else if (MODE == 1) {
        const float4 bb = *(const float4*)&bias[row];
        u16x4 o;
        o.x = f2bf(v[0] + bb.x); o.y = f2bf(v[1] + bb.y);
        o.z = f2bf(v[2] + bb.z); o.w = f2bf(v[3] + bb.w);
        *(u16x4*)((u16*)Outv + ((size_t)b * NPIX + col) * CH + row) = o;
      } else {
        const float bb = bias[col];
        float4 o = make_float4(v[0] + bb, v[1] + bb, v[2] + bb, v[3] + bb);
        *(float4*)((float*)Outv + ((size_t)b * CH + col) * NPIX + row) = o;
      }
    }
  }
}

// ---------------------------------------------------------------------------
// Depthwise 3x3, pixel-fast layout [b][c][n] (q,k paths). Unchanged.
// ---------------------------------------------------------------------------
__global__ __launch_bounds__(256) void dwconv(
    const u16* __restrict__ Pin, const float* __restrict__ Wd,
    const float* __restrict__ bd, u16* __restrict__ Outp) {
  __shared__ u16 s[34][40];
  const int t = threadIdx.x;
  const int bc = blockIdx.z;
  const int c = bc % CH;
  const u16* pin = Pin + (size_t)bc * NPIX;
  u16* pout = Outp + (size_t)bc * NPIX;
  float w[9];
#pragma unroll
  for (int i = 0; i < 9; ++i) w[i] = Wd[c * 9 + i];
  const float bb = bd[c];
  const int y0 = blockIdx.y * 32, x0 = blockIdx.x * 32;
  for (int idx = t; idx < 34 * 34; idx += 256) {
    const int hy = idx / 34, hx = idx - hy * 34;
    const int gy = y0 + hy - 1, gx = x0 + hx - 1;
    u16 v = 0;
    if (gy >= 0 && gy < 128 && gx >= 0 && gx < 128) v = pin[gy * 128 + gx];
    s[hy][hx] = v;
  }
  __syncthreads();
  const int py = (t >> 4) * 2, px = (t & 15) * 2;
#pragma unroll
  for (int dy = 0; dy < 2; ++dy)
#pragma unroll
    for (int dx = 0; dx < 2; ++dx) {
      const int oy = py + dy, ox = px + dx;
      float acc = bb;
#pragma unroll
      for (int i = 0; i < 3; ++i)
#pragma unroll
        for (int j = 0; j < 3; ++j)
          acc = fmaf(bf2f(s[oy + i][ox + j]), w[i * 3 + j], acc);
      pout[(y0 + oy) * 128 + x0 + ox] = f2bf(acc);
    }
}

// ---------------------------------------------------------------------------
// Depthwise 3x3, channel-fast layout [b][n][c] (v path).
// Block: 64 px (8x8 tile) x 4 channel-octets (32 ch). Grid (256, 12, NB).
// ---------------------------------------------------------------------------
__global__ __launch_bounds__(256) void dwconv_cf(
    const u16* __restrict__ Pin, const float* __restrict__ Wd,
    const float* __restrict__ bd, u16* __restrict__ Outp) {
  __shared__ float wls[32][9];
  __shared__ float bls[32];
  const int t = threadIdx.x;
  const int c0 = blockIdx.y * 32;
  const int b = blockIdx.z;
  for (int i = t; i < 32 * 9; i += 256) wls[i / 9][i % 9] = Wd[(c0 + i / 9) * 9 + i % 9];
  if (t < 32) bls[t] = bd[c0 + t];
  __syncthreads();
  const int oct = t & 3, p = t >> 2;
  const int y = (blockIdx.x >> 4) * 8 + (p >> 3);
  const int x = (blockIdx.x & 15) * 8 + (p & 7);
  const u16* pb = Pin + (size_t)b * NPIX * CH + c0 + oct * 8;
  float acc[8];
#pragma unroll
  for (int j = 0; j < 8; ++j) acc[j] = bls[oct * 8 + j];
#pragma unroll
  for (int dy = -1; dy <= 1; ++dy) {
    const int gy = y + dy;
    if (gy < 0 || gy > 127) continue;
#pragma unroll
    for (int dx = -1; dx <= 1; ++dx) {
      const int gx = x + dx;
      if (gx < 0 || gx > 127) continue;
      const int tap = (dy + 1) * 3 + (dx + 1);
      ushort8v in8 = *(const ushort8v*)(pb + (size_t)(gy * 128 + gx) * CH);
#pragma unroll
      for (int j = 0; j < 8; ++j)
        acc[j] = fmaf(bf2f(in8[j]), wls[oct * 8 + j][tap], acc[j]);
    }
  }
  ushort8v o;
#pragma unroll
  for (int j = 0; j < 8; ++j) o[j] = f2bf(acc[j]);
  *(ushort8v*)(Outp + ((size_t)b * NPIX + y * 128 + x) * CH + c0 + oct * 8) = o;
}

// ---------------------------------------------------------------------------
// Gram: per (b,h): G[c][d] += sum_n q[c][n]*k[d][n]; SQ += q^2; SK += k^2.
// Pixel-fast q,k. Grid (32 chunks, 64 bh), 64 threads.
// ---------------------------------------------------------------------------
__global__ __launch_bounds__(64) void gram48(
    const u16* __restrict__ Q, const u16* __restrict__ Kt,
    float* __restrict__ G, float* __restrict__ SQ, float* __restrict__ SK) {
  __shared__ u16 qs[48][72];
  __shared__ u16 ks[48][72];
  const int t = threadIdx.x;
  const int tc = t >> 3, td = t & 7;
  const int chunk = blockIdx.x, bh = blockIdx.y;
  const size_t base = ((size_t)(bh >> 3) * CH + (bh & 7) * 48) * NPIX + (size_t)chunk * 512;
  float acc[6][6];
#pragma unroll
  for (int i = 0; i < 6; ++i)
#pragma unroll
    for (int j = 0; j < 6; ++j) acc[i][j] = 0.f;
  float sq6[6] = {0, 0, 0, 0, 0, 0}, sk6[6] = {0, 0, 0, 0, 0, 0};

  for (int it = 0; it < 8; ++it) {
    for (int idx = t; idx < 384; idx += 64) {
      const int row = idx >> 3, seg = idx & 7;
      const size_t off = base + (size_t)row * NPIX + it * 64 + seg * 8;
      *(ushort8v*)&qs[row][seg * 8] = *(const ushort8v*)(Q + off);
      *(ushort8v*)&ks[row][seg * 8] = *(const ushort8v*)(Kt + off);
    }
    __syncthreads();
    for (int pp = 0; pp < 32; ++pp) {
      float2 qf[6], kf[6];
#pragma unroll
      for (int i = 0; i < 6; ++i) {
        const u32 qu = *(const u32*)&qs[tc * 6 + i][pp * 2];
        const u32 ku = *(const u32*)&ks[td * 6 + i][pp * 2];
        qf[i].x = __uint_as_float(qu << 16);
        qf[i].y = __uint_as_float(qu & 0xffff0000u);
        kf[i].x = __uint_as_float(ku << 16);
        kf[i].y = __uint_as_float(ku & 0xffff0000u);
      }
#pragma unroll
      for (int i = 0; i < 6; ++i)
#pragma unroll
        for (int j = 0; j < 6; ++j) {
          acc[i][j] = fmaf(qf[i].x, kf[j].x, acc[i][j]);
          acc[i][j] = fmaf(qf[i].y, kf[j].y, acc[i][j]);
        }
      if (td == 0)
#pragma unroll
        for (int i = 0; i < 6; ++i) sq6[i] += qf[i].x * qf[i].x + qf[i].y * qf[i].y;
      if (tc == 0)
#pragma unroll
        for (int j = 0; j < 6; ++j) sk6[j] += kf[j].x * kf[j].x + kf[j].y * kf[j].y;
    }
    __syncthreads();
  }
#pragma unroll
  for (int i = 0; i < 6; ++i)
#pragma unroll
    for (int j = 0; j < 6; ++j)
      atomicAdd(&G[((size_t)bh * 48 + tc * 6 + i) * 48 + td * 6 + j], acc[i][j]);
  if (td == 0)
#pragma unroll
    for (int i = 0; i < 6; ++i) atomicAdd(&SQ[bh * 48 + tc * 6 + i], sq6[i]);
  if (tc == 0)
#pragma unroll
    for (int j = 0; j < 6; ++j) atomicAdd(&SK[bh * 48 + td * 6 + j], sk6[j]);
}

// ---------------------------------------------------------------------------
// Attention + fold projection into M2 (bf16 [b][o][k], k fast).
// ---------------------------------------------------------------------------
__global__ __launch_bounds__(256) void attn_m2(
    const float* __restrict__ G, const float* __restrict__ SQ,
    const float* __restrict__ SK, const float* __restrict__ temp,
    const float* __restrict__ dc, const float* __restrict__ dl,
    const float* __restrict__ dp_w1, const float* __restrict__ dp_b1,
    const float* __restrict__ dp_w2, const float* __restrict__ dp_b2,
    const float* __restrict__ prj_w, u16* __restrict__ M2) {
  __shared__ float hid[48];
  __shared__ float Ard[48][49];
  __shared__ float pw_s[48][49];
  const int t = threadIdx.x;
  const int oc = blockIdx.x;
  const int bh = blockIdx.y;
  const int b = bh >> 3, h = bh & 7, h0 = h * 48;
  if (t < 48) {
    float s = dp_b1[t];
#pragma unroll
    for (int i = 0; i < 3; ++i) s += dc[b * 3 + i] * dp_w1[i * 48 + t];
    const float x3 = s * s * s;
    hid[t] = 0.5f * s * (1.f + tanhf(0.79788456080286536f * (s + 0.044715f * x3)));
  }
  for (int idx = t; idx < 48 * 48; idx += 256) {
    const int o = idx / 48, c2 = idx - o * 48;
    pw_s[o][c2] = prj_w[(size_t)(oc * 48 + o) * CH + h0 + c2];
  }
  __syncthreads();
  if (t < 48) {
    const int c = t;
    float dcp = dp_b2[h0 + c];
#pragma unroll
    for (int j = 0; j < 48; ++j) dcp += hid[j] * dp_w2[j * CH + h0 + c];
    const float rq = 1.f / fmaxf(sqrtf(SQ[bh * 48 + c]), 1e-12f);
    const float rowscale = temp[h] * dcp * dl[b] * rq;
    float vals[48];
    float m = -1e30f;
#pragma unroll
    for (int d = 0; d < 48; ++d) {
      const float rk = 1.f / fmaxf(sqrtf(SK[bh * 48 + d]), 1e-12f);
      const float v = G[((size_t)bh * 48 + c) * 48 + d] * rk * rowscale;
      vals[d] = v;
      m = fmaxf(m, v);
    }
    float ssum = 0.f;
#pragma unroll
    for (int d = 0; d < 48; ++d) {
      const float e = expf(vals[d] - m);
      vals[d] = e;
      ssum += e;
    }
    const float inv = 1.f / ssum;
#pragma unroll
    for (int d = 0; d < 48; ++d) Ard[c][d] = vals[d] * inv;
  }
  __syncthreads();
#pragma unroll
  for (int rIt = 0; rIt < 9; ++rIt) {
    const int idx = t + 256 * rIt;
    const int o = idx / 48, dd = idx - o * 48;
    float a = 0.f;
#pragma unroll
    for (int c2 = 0; c2 < 48; ++c2) a = fmaf(pw_s[o][c2], Ard[c2][dd], a);
    M2[((size_t)b * CH + oc * 48 + o) * CH + h0 + dd] = f2bf(a);
  }
}

__global__ void zero_f32(float* __restrict__ p, int n) {
  const int i = blockIdx.x * blockDim.x + threadIdx.x;
  if (i < n) p[i] = 0.f;
}

// ---------------------------------------------------------------------------
// ws: Xt (50.3M u16) | A (50.3M u16) | B (50.3M u16) | Wbf (3*147456 u16) |
//     M2 (8*147456 u16) | G | SQ | SK   (~306 MB)
// d_out doubles as scratch: halves hold q and k bf16 (dead before final GEMM).
// ---------------------------------------------------------------------------
extern "C" void kernel_launch(void* const* d_in, const int* in_sizes, int n_in,
                              void* d_out, int out_size, void* d_ws, size_t ws_size,
                              hipStream_t stream) {
  (void)in_sizes; (void)n_in; (void)out_size; (void)ws_size;
  const float* x      = (const float*)d_in[0];
  const float* dc     = (const float*)d_in[1];
  const float* dl     = (const float*)d_in[2];
  const float* temp   = (const float*)d_in[3];
  const float* prj_w  = (const float*)d_in[4];
  const float* prj_b  = (const float*)d_in[5];
  const float* dp_w1  = (const float*)d_in[6];
  const float* dp_b1  = (const float*)d_in[7];
  const float* dp_w2  = (const float*)d_in[8];
  const float* dp_b2  = (const float*)d_in[9];
  const float* wq_pw  = (const float*)d_in[10];
  const float* wq_pwb = (const float*)d_in[11];
  const float* wq_dw  = (const float*)d_in[12];
  const float* wq_dwb = (const float*)d_in[13];
  const float* wk_pw  = (const float*)d_in[14];
  const float* wk_pwb = (const float*)d_in[15];
  const float* wk_dw  = (const float*)d_in[16];
  const float* wk_dwb = (const float*)d_in[17];
  const float* wv_pw  = (const float*)d_in[18];
  const float* wv_pwb = (const float*)d_in[19];
  const float* wv_dw  = (const float*)d_in[20];
  const float* wv_dwb = (const float*)d_in[21];

  const size_t TEN = (size_t)NB * CH * NPIX;  // 50.3M elems
  u16* Xt = (u16*)d_ws;
  u16* A  = Xt + TEN;
  u16* B  = A + TEN;
  u16* Wbf = B + TEN;                 // 3 * CH*CH
  u16* M2 = Wbf + 3 * CH * CH;        // NB * CH*CH
  float* G  = (float*)(M2 + (size_t)NB * CH * CH);
  G = (float*)(((uintptr_t)G + 15) & ~(uintptr_t)15);
  float* SQ = G + 64 * 48 * 48;
  float* SK = SQ + 64 * 48;
  u16* D1 = (u16*)d_out;        // q (bf16) in first half of d_out
  u16* D2 = D1 + TEN;           // k (bf16) in second half
  float* out = (float*)d_out;

  const dim3 gG0(128, 3, NB);   // MODE 0/2: rows=n/p (128 tiles), cols=m/o (3)
  const dim3 gG1(3, 128, NB);   // MODE 1: rows=m (3), cols=n (128)
  const dim3 gDw(4, 4, NB * CH);
  const dim3 gDwCf(256, 12, NB);

  // prep: transpose X to token-major bf16; convert pw weights
  transpose_x<<<dim3(512, 12, NB), 256, 0, stream>>>(x, Xt);
  conv_w3<<<dim3((CH * CH + 255) / 256), 256, 0, stream>>>(wq_pw, wk_pw, wv_pw, Wbf);

  // q path
  gemm_mfma<0><<<gG0, 256, 0, stream>>>(Xt, Wbf, wq_pwb, A);
  dwconv<<<gDw, 256, 0, stream>>>(A, wq_dw, wq_dwb, D1);
  // k path
  gemm_mfma<0><<<gG0, 256, 0, stream>>>(Xt, Wbf + CH * CH, wk_pwb, A);
  dwconv<<<gDw, 256, 0, stream>>>(A, wk_dw, wk_dwb, D2);
  // gram + norms
  zero_f32<<<dim3((64 * 48 * 48 + 2 * 64 * 48 + 255) / 256), 256, 0, stream>>>(
      G, 64 * 48 * 48 + 2 * 64 * 48);
  gram48<<<dim3(32, 64), 64, 0, stream>>>(D1, D2, G, SQ, SK);
  // v path (channel-fast)
  gemm_mfma<1><<<gG1, 256, 0, stream>>>(Wbf + 2 * CH * CH, Xt, wv_pwb, A);
  dwconv_cf<<<gDwCf, 256, 0, stream>>>(A, wv_dw, wv_dwb, B);
  // attention + projection fold
  attn_m2<<<dim3(8, 64), 256, 0, stream>>>(G, SQ, SK, temp, dc, dl,
                                           dp_w1, dp_b1, dp_w2, dp_b2, prj_w, M2);
  // final GEMM: out[o][p] = sum_k M2[o][k] * Vt[p][k] + prj_b[o]
  gemm_mfma<2><<<gG0, 256, 0, stream>>>(B, M2, prj_b, out);
}

// Round 3
// 1173.174 us; speedup vs baseline: 2.2527x; 1.1297x over previous
//
#include <hip/hip_runtime.h>
#include <cstdint>

typedef unsigned short u16;
typedef unsigned int u32;
typedef __attribute__((ext_vector_type(8))) u16 ushort8v;
typedef __attribute__((ext_vector_type(4))) u16 u16x4;
typedef __attribute__((ext_vector_type(8))) short short8;
typedef __attribute__((ext_vector_type(4))) float f32x4;

#define CH 384
#define NPIX 16384
#define NB 8

static __device__ __forceinline__ float bf2f(u16 u) {
  return __uint_as_float(((u32)u) << 16);
}
static __device__ __forceinline__ u16 f2bf(float f) {
  u32 x = __float_as_uint(f);
  u32 r = (x + 0x7fffu + ((x >> 16) & 1u)) >> 16;
  return (u16)r;
}

static __device__ __forceinline__ void gload16(const u16* g, u16* l) {
  __builtin_amdgcn_global_load_lds(
      (const __attribute__((address_space(1))) void*)(uintptr_t)g,
      (__attribute__((address_space(3))) void*)(uintptr_t)l, 16, 0, 0);
}

// ---------------------------------------------------------------------------
// Transpose+convert: X f32 [b][c][n] -> Xt bf16 [b][n][c]. 32x32 tiles.
// ---------------------------------------------------------------------------
__global__ __launch_bounds__(256) void transpose_x(
    const float* __restrict__ X, u16* __restrict__ Xt) {
  __shared__ u16 tile[32][33];
  const int t = threadIdx.x;
  const int b = blockIdx.z;
  const int n0 = blockIdx.x * 32, c0 = blockIdx.y * 32;
  {
    const int cr = t >> 3, n4 = (t & 7) * 4;
    float4 v = *(const float4*)(X + ((size_t)b * CH + c0 + cr) * NPIX + n0 + n4);
    tile[cr][n4 + 0] = f2bf(v.x);
    tile[cr][n4 + 1] = f2bf(v.y);
    tile[cr][n4 + 2] = f2bf(v.z);
    tile[cr][n4 + 3] = f2bf(v.w);
  }
  __syncthreads();
  {
    const int nr = t >> 3, c4 = (t & 7) * 4;
    u16x4 o;
    o.x = tile[c4 + 0][nr];
    o.y = tile[c4 + 1][nr];
    o.z = tile[c4 + 2][nr];
    o.w = tile[c4 + 3][nr];
    *(u16x4*)(Xt + ((size_t)b * NPIX + n0 + nr) * CH + c0 + c4) = o;
  }
}

// Convert the 3 pointwise weights (384x384 f32) to bf16, packed consecutively.
__global__ __launch_bounds__(256) void conv_w3(
    const float* __restrict__ a, const float* __restrict__ bsrc,
    const float* __restrict__ c, u16* __restrict__ dst) {
  const int i = blockIdx.x * 256 + threadIdx.x;
  if (i < CH * CH) {
    dst[i] = f2bf(a[i]);
    dst[CH * CH + i] = f2bf(bsrc[i]);
    dst[2 * CH * CH + i] = f2bf(c[i]);
  }
}

// ---------------------------------------------------------------------------
// MFMA GEMM, 128x128 tile, BK=32, 4 waves (2x2 of 64x64), 16x16x32 bf16.
// 1D grid 3072, m-tile fastest + XCD swizzle: the 3 blocks sharing an Xt
// tile (different m) land consecutively on the same XCD -> L2 reuse.
// MODE 0: r=n (A=Xt, batched), c=m (B=W, shared);  out bf16 P[m][n] (pixel-fast)
// MODE 1: r=m (A=W, shared),  c=n (B=Xt, batched); out bf16 Pt[n][m] (chan-fast)
// MODE 2: r=p (A=Vt, batched), c=o (B=M2, batched); out f32  out[o][p]
// ---------------------------------------------------------------------------
template <int MODE>
__global__ __launch_bounds__(256) void gemm_mfma(
    const u16* __restrict__ Aop, const u16* __restrict__ Bop,
    const float* __restrict__ bias, void* __restrict__ Outv) {
  __shared__ u16 sm[8192];  // A tile [128][32] @0, B tile [128][32] @4096
  const int t = threadIdx.x;
  const int lane = t & 63, w = t >> 6;
  // --- XCD-aware decomposition (nwg=3072, 8 XCDs, cpx=384) ---
  const int bid = blockIdx.x;
  const int wg = (bid & 7) * 384 + (bid >> 3);
  const int mt = wg % 3;
  const int rest = wg / 3;
  const int nt = rest & 127;
  const int b = rest >> 7;
  const int r0 = (MODE == 1) ? mt * 128 : nt * 128;
  const int c0 = (MODE == 1) ? nt * 128 : mt * 128;

  const u16* Abase = (MODE == 1) ? (Aop + (size_t)r0 * CH)
                                 : (Aop + ((size_t)b * NPIX + r0) * CH);
  const u16* Bbase = (MODE == 0) ? (Bop + (size_t)c0 * CH)
                   : (MODE == 1) ? (Bop + ((size_t)b * NPIX + c0) * CH)
                                 : (Bop + ((size_t)b * CH + c0) * CH);

  const int wr = w >> 1, wc = w & 1;
  f32x4 acc[4][4] = {};
  const int srow = lane >> 2, scol = (lane & 3) * 8;
  const int fr = lane & 15, fg = lane >> 4;

  for (int k0 = 0; k0 < CH; k0 += 32) {
#pragma unroll
    for (int ii = 0; ii < 4; ++ii) {
      const int chunk = w * 4 + ii;  // 0..15
      const int c8 = chunk & 7;
      const u16* g = ((chunk < 8) ? Abase : Bbase) +
                     (size_t)(c8 * 16 + srow) * CH + k0 + scol;
      gload16(g, &sm[chunk * 512]);
    }
    __syncthreads();
    short8 a[4], bf[4];
#pragma unroll
    for (int rt = 0; rt < 4; ++rt)
      a[rt] = *(const short8*)&sm[(wr * 64 + rt * 16 + fr) * 32 + fg * 8];
#pragma unroll
    for (int ct = 0; ct < 4; ++ct)
      bf[ct] = *(const short8*)&sm[4096 + (wc * 64 + ct * 16 + fr) * 32 + fg * 8];
#pragma unroll
    for (int rt = 0; rt < 4; ++rt)
#pragma unroll
      for (int ct = 0; ct < 4; ++ct)
        acc[rt][ct] = __builtin_amdgcn_mfma_f32_16x16x32_bf16(
            a[rt], bf[ct], acc[rt][ct], 0, 0, 0);
    __syncthreads();
  }

#pragma unroll
  for (int rt = 0; rt < 4; ++rt) {
    const int row = r0 + wr * 64 + rt * 16 + fg * 4;  // + reg 0..3
#pragma unroll
    for (int ct = 0; ct < 4; ++ct) {
      const int col = c0 + wc * 64 + ct * 16 + fr;
      f32x4 v = acc[rt][ct];
      if (MODE == 0) {
        const float bb = bias[col];
        u16x4 o;
        o.x = f2bf(v[0] + bb); o.y = f2bf(v[1] + bb);
        o.z = f2bf(v[2] + bb); o.w = f2bf(v[3] + bb);
        *(u16x4*)((u16*)Outv + ((size_t)b * CH + col) * NPIX + row) = o;
      } else if (MODE == 1) {
        const float4 bb = *(const float4*)&bias[row];
        u16x4 o;
        o.x = f2bf(v[0] + bb.x); o.y = f2bf(v[1] + bb.y);
        o.z = f2bf(v[2] + bb.z); o.w = f2bf(v[3] + bb.w);
        *(u16x4*)((u16*)Outv + ((size_t)b * NPIX + col) * CH + row) = o;
      } else {
        const float bb = bias[col];
        float4 o = make_float4(v[0] + bb, v[1] + bb, v[2] + bb, v[3] + bb);
        *(float4*)((float*)Outv + ((size_t)b * CH + col) * NPIX + row) = o;
      }
    }
  }
}

// ---------------------------------------------------------------------------
// Depthwise 3x3, pixel-fast layout [b][c][n] (q,k paths).
// ---------------------------------------------------------------------------
__global__ __launch_bounds__(256) void dwconv(
    const u16* __restrict__ Pin, const float* __restrict__ Wd,
    const float* __restrict__ bd, u16* __restrict__ Outp) {
  __shared__ u16 s[34][40];
  const int t = threadIdx.x;
  const int bc = blockIdx.z;
  const int c = bc % CH;
  const u16* pin = Pin + (size_t)bc * NPIX;
  u16* pout = Outp + (size_t)bc * NPIX;
  float w[9];
#pragma unroll
  for (int i = 0; i < 9; ++i) w[i] = Wd[c * 9 + i];
  const float bb = bd[c];
  const int y0 = blockIdx.y * 32, x0 = blockIdx.x * 32;
  for (int idx = t; idx < 34 * 34; idx += 256) {
    const int hy = idx / 34, hx = idx - hy * 34;
    const int gy = y0 + hy - 1, gx = x0 + hx - 1;
    u16 v = 0;
    if (gy >= 0 && gy < 128 && gx >= 0 && gx < 128) v = pin[gy * 128 + gx];
    s[hy][hx] = v;
  }
  __syncthreads();
  const int py = (t >> 4) * 2, px = (t & 15) * 2;
#pragma unroll
  for (int dy = 0; dy < 2; ++dy)
#pragma unroll
    for (int dx = 0; dx < 2; ++dx) {
      const int oy = py + dy, ox = px + dx;
      float acc = bb;
#pragma unroll
      for (int i = 0; i < 3; ++i)
#pragma unroll
        for (int j = 0; j < 3; ++j)
          acc = fmaf(bf2f(s[oy + i][ox + j]), w[i * 3 + j], acc);
      pout[(y0 + oy) * 128 + x0 + ox] = f2bf(acc);
    }
}

// ---------------------------------------------------------------------------
// Depthwise 3x3, channel-fast layout [b][n][c] (v path).
// ---------------------------------------------------------------------------
__global__ __launch_bounds__(256) void dwconv_cf(
    const u16* __restrict__ Pin, const float* __restrict__ Wd,
    const float* __restrict__ bd, u16* __restrict__ Outp) {
  __shared__ float wls[32][9];
  __shared__ float bls[32];
  const int t = threadIdx.x;
  const int c0 = blockIdx.y * 32;
  const int b = blockIdx.z;
  for (int i = t; i < 32 * 9; i += 256) wls[i / 9][i % 9] = Wd[(c0 + i / 9) * 9 + i % 9];
  if (t < 32) bls[t] = bd[c0 + t];
  __syncthreads();
  const int oct = t & 3, p = t >> 2;
  const int y = (blockIdx.x >> 4) * 8 + (p >> 3);
  const int x = (blockIdx.x & 15) * 8 + (p & 7);
  const u16* pb = Pin + (size_t)b * NPIX * CH + c0 + oct * 8;
  float acc[8];
#pragma unroll
  for (int j = 0; j < 8; ++j) acc[j] = bls[oct * 8 + j];
#pragma unroll
  for (int dy = -1; dy <= 1; ++dy) {
    const int gy = y + dy;
    if (gy < 0 || gy > 127) continue;
#pragma unroll
    for (int dx = -1; dx <= 1; ++dx) {
      const int gx = x + dx;
      if (gx < 0 || gx > 127) continue;
      const int tap = (dy + 1) * 3 + (dx + 1);
      ushort8v in8 = *(const ushort8v*)(pb + (size_t)(gy * 128 + gx) * CH);
#pragma unroll
      for (int j = 0; j < 8; ++j)
        acc[j] = fmaf(bf2f(in8[j]), wls[oct * 8 + j][tap], acc[j]);
    }
  }
  ushort8v o;
#pragma unroll
  for (int j = 0; j < 8; ++j) o[j] = f2bf(acc[j]);
  *(ushort8v*)(Outp + ((size_t)b * NPIX + y * 128 + x) * CH + c0 + oct * 8) = o;
}

// ---------------------------------------------------------------------------
// MFMA gram: per (b,h): G[c][d] = sum_n q[c][n]*k[d][n] (48x48 = 3x3 MFMA
// tiles), SQ/SK from diagonals of q*q^T / k*k^T tiles. Fragments load
// directly from global (pixel-fast [row][n] IS the fragment layout).
// Grid (16 chunks of 1024 px, 64 bh), 256 threads = 4 waves (256 px each).
// Per-wave partials -> LDS -> block reduce -> global atomicAdd.
// ---------------------------------------------------------------------------
__global__ __launch_bounds__(256) void gram_mfma(
    const u16* __restrict__ Q, const u16* __restrict__ K,
    float* __restrict__ G, float* __restrict__ SQ, float* __restrict__ SK) {
  __shared__ float red[4][2400];  // per wave: G[48*48] then SQ[48], SK[48]
  const int t = threadIdx.x;
  const int lane = t & 63, w = t >> 6;
  const int chunk = blockIdx.x, bh = blockIdx.y;
  const int fr = lane & 15, fg = lane >> 4;
  const size_t base = ((size_t)(bh >> 3) * CH + (bh & 7) * 48) * NPIX +
                      (size_t)chunk * 1024 + w * 256 + fg * 8;
  const u16* qb = Q + base;
  const u16* kb = K + base;

  f32x4 acc[3][3] = {};
  f32x4 aq[3] = {};
  f32x4 ak[3] = {};

  for (int s = 0; s < 8; ++s) {
    const int so = s * 32;
    short8 a[3], bfr[3];
#pragma unroll
    for (int rt = 0; rt < 3; ++rt) {
      a[rt] = *(const short8*)(qb + (size_t)(rt * 16 + fr) * NPIX + so);
      bfr[rt] = *(const short8*)(kb + (size_t)(rt * 16 + fr) * NPIX + so);
    }
#pragma unroll
    for (int rt = 0; rt < 3; ++rt)
#pragma unroll
      for (int ct = 0; ct < 3; ++ct)
        acc[rt][ct] = __builtin_amdgcn_mfma_f32_16x16x32_bf16(
            a[rt], bfr[ct], acc[rt][ct], 0, 0, 0);
#pragma unroll
    for (int rt = 0; rt < 3; ++rt) {
      aq[rt] = __builtin_amdgcn_mfma_f32_16x16x32_bf16(a[rt], a[rt], aq[rt], 0, 0, 0);
      ak[rt] = __builtin_amdgcn_mfma_f32_16x16x32_bf16(bfr[rt], bfr[rt], ak[rt], 0, 0, 0);
    }
  }

  float* myr = red[w];
#pragma unroll
  for (int rt = 0; rt < 3; ++rt)
#pragma unroll
    for (int ct = 0; ct < 3; ++ct)
#pragma unroll
      for (int r = 0; r < 4; ++r)
        myr[(rt * 16 + fg * 4 + r) * 48 + ct * 16 + fr] = acc[rt][ct][r];
  if (fg == (fr >> 2)) {
    const int r = fr & 3;
#pragma unroll
    for (int rt = 0; rt < 3; ++rt) {
      myr[2304 + rt * 16 + fr] = aq[rt][r];
      myr[2352 + rt * 16 + fr] = ak[rt][r];
    }
  }
  __syncthreads();
  for (int e = t; e < 2400; e += 256) {
    const float s = red[0][e] + red[1][e] + red[2][e] + red[3][e];
    if (e < 2304)
      atomicAdd(&G[(size_t)bh * 2304 + e], s);
    else if (e < 2352)
      atomicAdd(&SQ[bh * 48 + (e - 2304)], s);
    else
      atomicAdd(&SK[bh * 48 + (e - 2352)], s);
  }
}

// ---------------------------------------------------------------------------
// Attention + fold projection into M2 (bf16 [b][o][k], k fast).
// ---------------------------------------------------------------------------
__global__ __launch_bounds__(256) void attn_m2(
    const float* __restrict__ G, const float* __restrict__ SQ,
    const float* __restrict__ SK, const float* __restrict__ temp,
    const float* __restrict__ dc, const float* __restrict__ dl,
    const float* __restrict__ dp_w1, const float* __restrict__ dp_b1,
    const float* __restrict__ dp_w2, const float* __restrict__ dp_b2,
    const float* __restrict__ prj_w, u16* __restrict__ M2) {
  __shared__ float hid[48];
  __shared__ float Ard[48][49];
  __shared__ float pw_s[48][49];
  const int t = threadIdx.x;
  const int oc = blockIdx.x;
  const int bh = blockIdx.y;
  const int b = bh >> 3, h = bh & 7, h0 = h * 48;
  if (t < 48) {
    float s = dp_b1[t];
#pragma unroll
    for (int i = 0; i < 3; ++i) s += dc[b * 3 + i] * dp_w1[i * 48 + t];
    const float x3 = s * s * s;
    hid[t] = 0.5f * s * (1.f + tanhf(0.79788456080286536f * (s + 0.044715f * x3)));
  }
  for (int idx = t; idx < 48 * 48; idx += 256) {
    const int o = idx / 48, c2 = idx - o * 48;
    pw_s[o][c2] = prj_w[(size_t)(oc * 48 + o) * CH + h0 + c2];
  }
  __syncthreads();
  if (t < 48) {
    const int c = t;
    float dcp = dp_b2[h0 + c];
#pragma unroll
    for (int j = 0; j < 48; ++j) dcp += hid[j] * dp_w2[j * CH + h0 + c];
    const float rq = 1.f / fmaxf(sqrtf(SQ[bh * 48 + c]), 1e-12f);
    const float rowscale = temp[h] * dcp * dl[b] * rq;
    float vals[48];
    float m = -1e30f;
#pragma unroll
    for (int d = 0; d < 48; ++d) {
      const float rk = 1.f / fmaxf(sqrtf(SK[bh * 48 + d]), 1e-12f);
      const float v = G[((size_t)bh * 48 + c) * 48 + d] * rk * rowscale;
      vals[d] = v;
      m = fmaxf(m, v);
    }
    float ssum = 0.f;
#pragma unroll
    for (int d = 0; d < 48; ++d) {
      const float e = expf(vals[d] - m);
      vals[d] = e;
      ssum += e;
    }
    const float inv = 1.f / ssum;
#pragma unroll
    for (int d = 0; d < 48; ++d) Ard[c][d] = vals[d] * inv;
  }
  __syncthreads();
#pragma unroll
  for (int rIt = 0; rIt < 9; ++rIt) {
    const int idx = t + 256 * rIt;
    const int o = idx / 48, dd = idx - o * 48;
    float a = 0.f;
#pragma unroll
    for (int c2 = 0; c2 < 48; ++c2) a = fmaf(pw_s[o][c2], Ard[c2][dd], a);
    M2[((size_t)b * CH + oc * 48 + o) * CH + h0 + dd] = f2bf(a);
  }
}

__global__ void zero_f32(float* __restrict__ p, int n) {
  const int i = blockIdx.x * blockDim.x + threadIdx.x;
  if (i < n) p[i] = 0.f;
}

// ---------------------------------------------------------------------------
// ws: Xt (50.3M u16) | A (50.3M u16) | B (50.3M u16) | Wbf (3*147456 u16) |
//     M2 (NB*147456 u16) | G | SQ | SK   (~306 MB)
// d_out doubles as scratch: halves hold q and k bf16 (dead before final GEMM).
// ---------------------------------------------------------------------------
extern "C" void kernel_launch(void* const* d_in, const int* in_sizes, int n_in,
                              void* d_out, int out_size, void* d_ws, size_t ws_size,
                              hipStream_t stream) {
  (void)in_sizes; (void)n_in; (void)out_size; (void)ws_size;
  const float* x      = (const float*)d_in[0];
  const float* dc     = (const float*)d_in[1];
  const float* dl     = (const float*)d_in[2];
  const float* temp   = (const float*)d_in[3];
  const float* prj_w  = (const float*)d_in[4];
  const float* prj_b  = (const float*)d_in[5];
  const float* dp_w1  = (const float*)d_in[6];
  const float* dp_b1  = (const float*)d_in[7];
  const float* dp_w2  = (const float*)d_in[8];
  const float* dp_b2  = (const float*)d_in[9];
  const float* wq_pw  = (const float*)d_in[10];
  const float* wq_pwb = (const float*)d_in[11];
  const float* wq_dw  = (const float*)d_in[12];
  const float* wq_dwb = (const float*)d_in[13];
  const float* wk_pw  = (const float*)d_in[14];
  const float* wk_pwb = (const float*)d_in[15];
  const float* wk_dw  = (const float*)d_in[16];
  const float* wk_dwb = (const float*)d_in[17];
  const float* wv_pw  = (const float*)d_in[18];
  const float* wv_pwb = (const float*)d_in[19];
  const float* wv_dw  = (const float*)d_in[20];
  const float* wv_dwb = (const float*)d_in[21];

  const size_t TEN = (size_t)NB * CH * NPIX;  // 50.3M elems
  u16* Xt = (u16*)d_ws;
  u16* A  = Xt + TEN;
  u16* B  = A + TEN;
  u16* Wbf = B + TEN;                 // 3 * CH*CH
  u16* M2 = Wbf + 3 * CH * CH;        // NB * CH*CH
  float* G  = (float*)(M2 + (size_t)NB * CH * CH);
  G = (float*)(((uintptr_t)G + 15) & ~(uintptr_t)15);
  float* SQ = G + 64 * 48 * 48;
  float* SK = SQ + 64 * 48;
  u16* D1 = (u16*)d_out;        // q (bf16) in first half of d_out
  u16* D2 = D1 + TEN;           // k (bf16) in second half
  float* out = (float*)d_out;

  const dim3 gG(3072);          // 1D, XCD-swizzled inside
  const dim3 gDw(4, 4, NB * CH);
  const dim3 gDwCf(256, 12, NB);

  // prep: transpose X to token-major bf16; convert pw weights
  transpose_x<<<dim3(512, 12, NB), 256, 0, stream>>>(x, Xt);
  conv_w3<<<dim3((CH * CH + 255) / 256), 256, 0, stream>>>(wq_pw, wk_pw, wv_pw, Wbf);

  // q path
  gemm_mfma<0><<<gG, 256, 0, stream>>>(Xt, Wbf, wq_pwb, A);
  dwconv<<<gDw, 256, 0, stream>>>(A, wq_dw, wq_dwb, D1);
  // k path
  gemm_mfma<0><<<gG, 256, 0, stream>>>(Xt, Wbf + CH * CH, wk_pwb, A);
  dwconv<<<gDw, 256, 0, stream>>>(A, wk_dw, wk_dwb, D2);
  // gram + norms (zero the atomic targets first; ws is poisoned 0xAA)
  zero_f32<<<dim3((64 * 48 * 48 + 2 * 64 * 48 + 255) / 256), 256, 0, stream>>>(
      G, 64 * 48 * 48 + 2 * 64 * 48);
  gram_mfma<<<dim3(16, 64), 256, 0, stream>>>(D1, D2, G, SQ, SK);
  // v path (channel-fast)
  gemm_mfma<1><<<gG, 256, 0, stream>>>(Wbf + 2 * CH * CH, Xt, wv_pwb, A);
  dwconv_cf<<<gDwCf, 256, 0, stream>>>(A, wv_dw, wv_dwb, B);
  // attention + projection fold
  attn_m2<<<dim3(8, 64), 256, 0, stream>>>(G, SQ, SK, temp, dc, dl,
                                           dp_w1, dp_b1, dp_w2, dp_b2, prj_w, M2);
  // final GEMM: out[o][p] = sum_k M2[o][k] * Vt[p][k] + prj_b[o]
  gemm_mfma<2><<<gG, 256, 0, stream>>>(B, M2, prj_b, out);
}

// Round 4
// 940.271 us; speedup vs baseline: 2.8107x; 1.2477x over previous
//
#include <hip/hip_runtime.h>
#include <cstdint>

typedef unsigned short u16;
typedef unsigned int u32;
typedef __attribute__((ext_vector_type(8))) u16 ushort8v;
typedef __attribute__((ext_vector_type(4))) u16 u16x4;
typedef __attribute__((ext_vector_type(8))) short short8;
typedef __attribute__((ext_vector_type(4))) float f32x4;

#define CH 384
#define NPIX 16384
#define NB 8

static __device__ __forceinline__ float bf2f(u16 u) {
  return __uint_as_float(((u32)u) << 16);
}
static __device__ __forceinline__ u16 f2bf(float f) {
  u32 x = __float_as_uint(f);
  u32 r = (x + 0x7fffu + ((x >> 16) & 1u)) >> 16;
  return (u16)r;
}

static __device__ __forceinline__ void gload16(const u16* g, u16* l) {
  __builtin_amdgcn_global_load_lds(
      (const __attribute__((address_space(1))) void*)(uintptr_t)g,
      (__attribute__((address_space(3))) void*)(uintptr_t)l, 16, 0, 0);
}

// ---------------------------------------------------------------------------
// Transpose+convert: X f32 [b][c][n] -> Xt bf16 [b][n][c]. 32x32 tiles.
// ---------------------------------------------------------------------------
__global__ __launch_bounds__(256) void transpose_x(
    const float* __restrict__ X, u16* __restrict__ Xt) {
  __shared__ u16 tile[32][33];
  const int t = threadIdx.x;
  const int b = blockIdx.z;
  const int n0 = blockIdx.x * 32, c0 = blockIdx.y * 32;
  {
    const int cr = t >> 3, n4 = (t & 7) * 4;
    float4 v = *(const float4*)(X + ((size_t)b * CH + c0 + cr) * NPIX + n0 + n4);
    tile[cr][n4 + 0] = f2bf(v.x);
    tile[cr][n4 + 1] = f2bf(v.y);
    tile[cr][n4 + 2] = f2bf(v.z);
    tile[cr][n4 + 3] = f2bf(v.w);
  }
  __syncthreads();
  {
    const int nr = t >> 3, c4 = (t & 7) * 4;
    u16x4 o;
    o.x = tile[c4 + 0][nr];
    o.y = tile[c4 + 1][nr];
    o.z = tile[c4 + 2][nr];
    o.w = tile[c4 + 3][nr];
    *(u16x4*)(Xt + ((size_t)b * NPIX + n0 + nr) * CH + c0 + c4) = o;
  }
}

// Convert the 3 pointwise weights (384x384 f32) to bf16, packed consecutively.
__global__ __launch_bounds__(256) void conv_w3(
    const float* __restrict__ a, const float* __restrict__ bsrc,
    const float* __restrict__ c, u16* __restrict__ dst) {
  const int i = blockIdx.x * 256 + threadIdx.x;
  if (i < CH * CH) {
    dst[i] = f2bf(a[i]);
    dst[CH * CH + i] = f2bf(bsrc[i]);
    dst[2 * CH * CH + i] = f2bf(c[i]);
  }
}

// ---------------------------------------------------------------------------
// MFMA GEMM, 128x128 tile, BK=32, 4 waves (2x2 of 64x64), 16x16x32 bf16.
// 1D grid 3072, m-tile fastest + XCD swizzle.
// MODE 0: r=n (A=Xt, batched), c=m (B=W, shared);  out bf16 P[m][n] (pixel-fast)
// MODE 1: r=m (A=W, shared),  c=n (B=Xt, batched); out bf16 Pt[n][m] (chan-fast)
// MODE 2: r=p (A=Vt, batched), c=o (B=M2, batched); out f32  out[o][p]
// ---------------------------------------------------------------------------
template <int MODE>
__global__ __launch_bounds__(256) void gemm_mfma(
    const u16* __restrict__ Aop, const u16* __restrict__ Bop,
    const float* __restrict__ bias, void* __restrict__ Outv) {
  __shared__ u16 sm[8192];  // A tile [128][32] @0, B tile [128][32] @4096
  const int t = threadIdx.x;
  const int lane = t & 63, w = t >> 6;
  const int bid = blockIdx.x;
  const int wg = (bid & 7) * 384 + (bid >> 3);
  const int mt = wg % 3;
  const int rest = wg / 3;
  const int nt = rest & 127;
  const int b = rest >> 7;
  const int r0 = (MODE == 1) ? mt * 128 : nt * 128;
  const int c0 = (MODE == 1) ? nt * 128 : mt * 128;

  const u16* Abase = (MODE == 1) ? (Aop + (size_t)r0 * CH)
                                 : (Aop + ((size_t)b * NPIX + r0) * CH);
  const u16* Bbase = (MODE == 0) ? (Bop + (size_t)c0 * CH)
                   : (MODE == 1) ? (Bop + ((size_t)b * NPIX + c0) * CH)
                                 : (Bop + ((size_t)b * CH + c0) * CH);

  const int wr = w >> 1, wc = w & 1;
  f32x4 acc[4][4] = {};
  const int srow = lane >> 2, scol = (lane & 3) * 8;
  const int fr = lane & 15, fg = lane >> 4;

  for (int k0 = 0; k0 < CH; k0 += 32) {
#pragma unroll
    for (int ii = 0; ii < 4; ++ii) {
      const int chunk = w * 4 + ii;  // 0..15
      const int c8 = chunk & 7;
      const u16* g = ((chunk < 8) ? Abase : Bbase) +
                     (size_t)(c8 * 16 + srow) * CH + k0 + scol;
      gload16(g, &sm[chunk * 512]);
    }
    __syncthreads();
    short8 a[4], bf[4];
#pragma unroll
    for (int rt = 0; rt < 4; ++rt)
      a[rt] = *(const short8*)&sm[(wr * 64 + rt * 16 + fr) * 32 + fg * 8];
#pragma unroll
    for (int ct = 0; ct < 4; ++ct)
      bf[ct] = *(const short8*)&sm[4096 + (wc * 64 + ct * 16 + fr) * 32 + fg * 8];
#pragma unroll
    for (int rt = 0; rt < 4; ++rt)
#pragma unroll
      for (int ct = 0; ct < 4; ++ct)
        acc[rt][ct] = __builtin_amdgcn_mfma_f32_16x16x32_bf16(
            a[rt], bf[ct], acc[rt][ct], 0, 0, 0);
    __syncthreads();
  }

#pragma unroll
  for (int rt = 0; rt < 4; ++rt) {
    const int row = r0 + wr * 64 + rt * 16 + fg * 4;  // + reg 0..3
#pragma unroll
    for (int ct = 0; ct < 4; ++ct) {
      const int col = c0 + wc * 64 + ct * 16 + fr;
      f32x4 v = acc[rt][ct];
      if (MODE == 0) {
        const float bb = bias[col];
        u16x4 o;
        o.x = f2bf(v[0] + bb); o.y = f2bf(v[1] + bb);
        o.z = f2bf(v[2] + bb); o.w = f2bf(v[3] + bb);
        *(u16x4*)((u16*)Outv + ((size_t)b * CH + col) * NPIX + row) = o;
      } else if (MODE == 1) {
        const float4 bb = *(const float4*)&bias[row];
        u16x4 o;
        o.x = f2bf(v[0] + bb.x); o.y = f2bf(v[1] + bb.y);
        o.z = f2bf(v[2] + bb.z); o.w = f2bf(v[3] + bb.w);
        *(u16x4*)((u16*)Outv + ((size_t)b * NPIX + col) * CH + row) = o;
      } else {
        const float bb = bias[col];
        float4 o = make_float4(v[0] + bb, v[1] + bb, v[2] + bb, v[3] + bb);
        *(float4*)((float*)Outv + ((size_t)b * CH + col) * NPIX + row) = o;
      }
    }
  }
}

// ---------------------------------------------------------------------------
// Depthwise 3x3, pixel-fast, whole-plane-in-LDS. One block per (b,c) plane.
// Stage 32KB plane coalesced (16B/lane), each thread computes an 8x8 tile
// with a 3-row sliding f32 register window, stores 16B/lane coalesced.
// ---------------------------------------------------------------------------
__global__ __launch_bounds__(256) void dwconv_plane(
    const u16* __restrict__ Pin, const float* __restrict__ Wd,
    const float* __restrict__ bd, u16* __restrict__ Outp) {
  __shared__ u16 plane[128][136];  // row stride 272B (16B-aligned)
  const int t = threadIdx.x;
  const int bc = blockIdx.x;
  const int c = bc % CH;
  const u16* pin = Pin + (size_t)bc * NPIX;
  u16* pout = Outp + (size_t)bc * NPIX;
  float w[9];
#pragma unroll
  for (int i = 0; i < 9; ++i) w[i] = Wd[c * 9 + i];
  const float bb = bd[c];
#pragma unroll
  for (int i = 0; i < 8; ++i) {
    const int idx = t + 256 * i;  // 0..2047
    const int row = idx >> 4, col8 = (idx & 15) * 8;
    *(ushort8v*)&plane[row][col8] = *(const ushort8v*)(pin + row * 128 + col8);
  }
  __syncthreads();
  const int ty = t >> 4, tx = t & 15;
  const int x0 = tx * 8, y0 = ty * 8;
  float r0[10], r1[10], r2[10];
  auto ldrow = [&](int gy, float* r) {
    if (gy < 0 || gy > 127) {
#pragma unroll
      for (int i = 0; i < 10; ++i) r[i] = 0.f;
      return;
    }
    ushort8v v = *(const ushort8v*)&plane[gy][x0];
#pragma unroll
    for (int j = 0; j < 8; ++j) r[1 + j] = bf2f(v[j]);
    r[0] = (tx == 0) ? 0.f : bf2f(plane[gy][x0 - 1]);
    r[9] = (tx == 15) ? 0.f : bf2f(plane[gy][x0 + 8]);
  };
  ldrow(y0 - 1, r0);
  ldrow(y0, r1);
#pragma unroll
  for (int oy = 0; oy < 8; ++oy) {
    ldrow(y0 + oy + 1, r2);
    ushort8v o;
#pragma unroll
    for (int j = 0; j < 8; ++j) {
      float acc = bb;
      acc = fmaf(r0[j], w[0], acc);
      acc = fmaf(r0[j + 1], w[1], acc);
      acc = fmaf(r0[j + 2], w[2], acc);
      acc = fmaf(r1[j], w[3], acc);
      acc = fmaf(r1[j + 1], w[4], acc);
      acc = fmaf(r1[j + 2], w[5], acc);
      acc = fmaf(r2[j], w[6], acc);
      acc = fmaf(r2[j + 1], w[7], acc);
      acc = fmaf(r2[j + 2], w[8], acc);
      o[j] = f2bf(acc);
    }
    *(ushort8v*)(pout + (y0 + oy) * 128 + x0) = o;
#pragma unroll
    for (int i = 0; i < 10; ++i) {
      r0[i] = r1[i];
      r1[i] = r2[i];
    }
  }
}

// ---------------------------------------------------------------------------
// Depthwise 3x3, channel-fast layout [b][n][c] (v path).
// ---------------------------------------------------------------------------
__global__ __launch_bounds__(256) void dwconv_cf(
    const u16* __restrict__ Pin, const float* __restrict__ Wd,
    const float* __restrict__ bd, u16* __restrict__ Outp) {
  __shared__ float wls[32][9];
  __shared__ float bls[32];
  const int t = threadIdx.x;
  const int c0 = blockIdx.y * 32;
  const int b = blockIdx.z;
  for (int i = t; i < 32 * 9; i += 256) wls[i / 9][i % 9] = Wd[(c0 + i / 9) * 9 + i % 9];
  if (t < 32) bls[t] = bd[c0 + t];
  __syncthreads();
  const int oct = t & 3, p = t >> 2;
  const int y = (blockIdx.x >> 4) * 8 + (p >> 3);
  const int x = (blockIdx.x & 15) * 8 + (p & 7);
  const u16* pb = Pin + (size_t)b * NPIX * CH + c0 + oct * 8;
  float acc[8];
#pragma unroll
  for (int j = 0; j < 8; ++j) acc[j] = bls[oct * 8 + j];
#pragma unroll
  for (int dy = -1; dy <= 1; ++dy) {
    const int gy = y + dy;
    if (gy < 0 || gy > 127) continue;
#pragma unroll
    for (int dx = -1; dx <= 1; ++dx) {
      const int gx = x + dx;
      if (gx < 0 || gx > 127) continue;
      const int tap = (dy + 1) * 3 + (dx + 1);
      ushort8v in8 = *(const ushort8v*)(pb + (size_t)(gy * 128 + gx) * CH);
#pragma unroll
      for (int j = 0; j < 8; ++j)
        acc[j] = fmaf(bf2f(in8[j]), wls[oct * 8 + j][tap], acc[j]);
    }
  }
  ushort8v o;
#pragma unroll
  for (int j = 0; j < 8; ++j) o[j] = f2bf(acc[j]);
  *(ushort8v*)(Outp + ((size_t)b * NPIX + y * 128 + x) * CH + c0 + oct * 8) = o;
}

// ---------------------------------------------------------------------------
// MFMA gram: per (b,h): G = q k^T (3x3 MFMA tiles), SQ/SK from diagonals.
// ---------------------------------------------------------------------------
__global__ __launch_bounds__(256) void gram_mfma(
    const u16* __restrict__ Q, const u16* __restrict__ K,
    float* __restrict__ G, float* __restrict__ SQ, float* __restrict__ SK) {
  __shared__ float red[4][2400];
  const int t = threadIdx.x;
  const int lane = t & 63, w = t >> 6;
  const int chunk = blockIdx.x, bh = blockIdx.y;
  const int fr = lane & 15, fg = lane >> 4;
  const size_t base = ((size_t)(bh >> 3) * CH + (bh & 7) * 48) * NPIX +
                      (size_t)chunk * 1024 + w * 256 + fg * 8;
  const u16* qb = Q + base;
  const u16* kb = K + base;

  f32x4 acc[3][3] = {};
  f32x4 aq[3] = {};
  f32x4 ak[3] = {};

  for (int s = 0; s < 8; ++s) {
    const int so = s * 32;
    short8 a[3], bfr[3];
#pragma unroll
    for (int rt = 0; rt < 3; ++rt) {
      a[rt] = *(const short8*)(qb + (size_t)(rt * 16 + fr) * NPIX + so);
      bfr[rt] = *(const short8*)(kb + (size_t)(rt * 16 + fr) * NPIX + so);
    }
#pragma unroll
    for (int rt = 0; rt < 3; ++rt)
#pragma unroll
      for (int ct = 0; ct < 3; ++ct)
        acc[rt][ct] = __builtin_amdgcn_mfma_f32_16x16x32_bf16(
            a[rt], bfr[ct], acc[rt][ct], 0, 0, 0);
#pragma unroll
    for (int rt = 0; rt < 3; ++rt) {
      aq[rt] = __builtin_amdgcn_mfma_f32_16x16x32_bf16(a[rt], a[rt], aq[rt], 0, 0, 0);
      ak[rt] = __builtin_amdgcn_mfma_f32_16x16x32_bf16(bfr[rt], bfr[rt], ak[rt], 0, 0, 0);
    }
  }

  float* myr = red[w];
#pragma unroll
  for (int rt = 0; rt < 3; ++rt)
#pragma unroll
    for (int ct = 0; ct < 3; ++ct)
#pragma unroll
      for (int r = 0; r < 4; ++r)
        myr[(rt * 16 + fg * 4 + r) * 48 + ct * 16 + fr] = acc[rt][ct][r];
  if (fg == (fr >> 2)) {
    const int r = fr & 3;
#pragma unroll
    for (int rt = 0; rt < 3; ++rt) {
      myr[2304 + rt * 16 + fr] = aq[rt][r];
      myr[2352 + rt * 16 + fr] = ak[rt][r];
    }
  }
  __syncthreads();
  for (int e = t; e < 2400; e += 256) {
    const float s = red[0][e] + red[1][e] + red[2][e] + red[3][e];
    if (e < 2304)
      atomicAdd(&G[(size_t)bh * 2304 + e], s);
    else if (e < 2352)
      atomicAdd(&SQ[bh * 48 + (e - 2304)], s);
    else
      atomicAdd(&SK[bh * 48 + (e - 2352)], s);
  }
}

// ---------------------------------------------------------------------------
// Attention + fold projection into M2 (bf16 [b][o][k], k fast).
// ---------------------------------------------------------------------------
__global__ __launch_bounds__(256) void attn_m2(
    const float* __restrict__ G, const float* __restrict__ SQ,
    const float* __restrict__ SK, const float* __restrict__ temp,
    const float* __restrict__ dc, const float* __restrict__ dl,
    const float* __restrict__ dp_w1, const float* __restrict__ dp_b1,
    const float* __restrict__ dp_w2, const float* __restrict__ dp_b2,
    const float* __restrict__ prj_w, u16* __restrict__ M2) {
  __shared__ float hid[48];
  __shared__ float Ard[48][49];
  __shared__ float pw_s[48][49];
  const int t = threadIdx.x;
  const int oc = blockIdx.x;
  const int bh = blockIdx.y;
  const int b = bh >> 3, h = bh & 7, h0 = h * 48;
  if (t < 48) {
    float s = dp_b1[t];
#pragma unroll
    for (int i = 0; i < 3; ++i) s += dc[b * 3 + i] * dp_w1[i * 48 + t];
    const float x3 = s * s * s;
    hid[t] = 0.5f * s * (1.f + tanhf(0.79788456080286536f * (s + 0.044715f * x3)));
  }
  for (int idx = t; idx < 48 * 48; idx += 256) {
    const int o = idx / 48, c2 = idx - o * 48;
    pw_s[o][c2] = prj_w[(size_t)(oc * 48 + o) * CH + h0 + c2];
  }
  __syncthreads();
  if (t < 48) {
    const int c = t;
    float dcp = dp_b2[h0 + c];
#pragma unroll
    for (int j = 0; j < 48; ++j) dcp += hid[j] * dp_w2[j * CH + h0 + c];
    const float rq = 1.f / fmaxf(sqrtf(SQ[bh * 48 + c]), 1e-12f);
    const float rowscale = temp[h] * dcp * dl[b] * rq;
    float vals[48];
    float m = -1e30f;
#pragma unroll
    for (int d = 0; d < 48; ++d) {
      const float rk = 1.f / fmaxf(sqrtf(SK[bh * 48 + d]), 1e-12f);
      const float v = G[((size_t)bh * 48 + c) * 48 + d] * rk * rowscale;
      vals[d] = v;
      m = fmaxf(m, v);
    }
    float ssum = 0.f;
#pragma unroll
    for (int d = 0; d < 48; ++d) {
      const float e = expf(vals[d] - m);
      vals[d] = e;
      ssum += e;
    }
    const float inv = 1.f / ssum;
#pragma unroll
    for (int d = 0; d < 48; ++d) Ard[c][d] = vals[d] * inv;
  }
  __syncthreads();
#pragma unroll
  for (int rIt = 0; rIt < 9; ++rIt) {
    const int idx = t + 256 * rIt;
    const int o = idx / 48, dd = idx - o * 48;
    float a = 0.f;
#pragma unroll
    for (int c2 = 0; c2 < 48; ++c2) a = fmaf(pw_s[o][c2], Ard[c2][dd], a);
    M2[((size_t)b * CH + oc * 48 + o) * CH + h0 + dd] = f2bf(a);
  }
}

__global__ void zero_f32(float* __restrict__ p, int n) {
  const int i = blockIdx.x * blockDim.x + threadIdx.x;
  if (i < n) p[i] = 0.f;
}

// ---------------------------------------------------------------------------
// ws: Xt | A | B (bf16 tensors) | Wbf | M2 | G | SQ | SK  (~306 MB)
// d_out halves hold q and k bf16 (dead before final GEMM writes it).
// ---------------------------------------------------------------------------
extern "C" void kernel_launch(void* const* d_in, const int* in_sizes, int n_in,
                              void* d_out, int out_size, void* d_ws, size_t ws_size,
                              hipStream_t stream) {
  (void)in_sizes; (void)n_in; (void)out_size; (void)ws_size;
  const float* x      = (const float*)d_in[0];
  const float* dc     = (const float*)d_in[1];
  const float* dl     = (const float*)d_in[2];
  const float* temp   = (const float*)d_in[3];
  const float* prj_w  = (const float*)d_in[4];
  const float* prj_b  = (const float*)d_in[5];
  const float* dp_w1  = (const float*)d_in[6];
  const float* dp_b1  = (const float*)d_in[7];
  const float* dp_w2  = (const float*)d_in[8];
  const float* dp_b2  = (const float*)d_in[9];
  const float* wq_pw  = (const float*)d_in[10];
  const float* wq_pwb = (const float*)d_in[11];
  const float* wq_dw  = (const float*)d_in[12];
  const float* wq_dwb = (const float*)d_in[13];
  const float* wk_pw  = (const float*)d_in[14];
  const float* wk_pwb = (const float*)d_in[15];
  const float* wk_dw  = (const float*)d_in[16];
  const float* wk_dwb = (const float*)d_in[17];
  const float* wv_pw  = (const float*)d_in[18];
  const float* wv_pwb = (const float*)d_in[19];
  const float* wv_dw  = (const float*)d_in[20];
  const float* wv_dwb = (const float*)d_in[21];

  const size_t TEN = (size_t)NB * CH * NPIX;  // 50.3M elems
  u16* Xt = (u16*)d_ws;
  u16* A  = Xt + TEN;
  u16* B  = A + TEN;
  u16* Wbf = B + TEN;                 // 3 * CH*CH
  u16* M2 = Wbf + 3 * CH * CH;        // NB * CH*CH
  float* G  = (float*)(M2 + (size_t)NB * CH * CH);
  G = (float*)(((uintptr_t)G + 15) & ~(uintptr_t)15);
  float* SQ = G + 64 * 48 * 48;
  float* SK = SQ + 64 * 48;
  u16* D1 = (u16*)d_out;        // q (bf16) in first half of d_out
  u16* D2 = D1 + TEN;           // k (bf16) in second half
  float* out = (float*)d_out;

  const dim3 gG(3072);          // 1D, XCD-swizzled inside
  const dim3 gDwP(NB * CH);     // one block per (b,c) plane
  const dim3 gDwCf(256, 12, NB);

  // prep: transpose X to token-major bf16; convert pw weights
  transpose_x<<<dim3(512, 12, NB), 256, 0, stream>>>(x, Xt);
  conv_w3<<<dim3((CH * CH + 255) / 256), 256, 0, stream>>>(wq_pw, wk_pw, wv_pw, Wbf);

  // q path
  gemm_mfma<0><<<gG, 256, 0, stream>>>(Xt, Wbf, wq_pwb, A);
  dwconv_plane<<<gDwP, 256, 0, stream>>>(A, wq_dw, wq_dwb, D1);
  // k path
  gemm_mfma<0><<<gG, 256, 0, stream>>>(Xt, Wbf + CH * CH, wk_pwb, A);
  dwconv_plane<<<gDwP, 256, 0, stream>>>(A, wk_dw, wk_dwb, D2);
  // gram + norms (zero the atomic targets first; ws is poisoned 0xAA)
  zero_f32<<<dim3((64 * 48 * 48 + 2 * 64 * 48 + 255) / 256), 256, 0, stream>>>(
      G, 64 * 48 * 48 + 2 * 64 * 48);
  gram_mfma<<<dim3(16, 64), 256, 0, stream>>>(D1, D2, G, SQ, SK);
  // v path (channel-fast)
  gemm_mfma<1><<<gG, 256, 0, stream>>>(Wbf + 2 * CH * CH, Xt, wv_pwb, A);
  dwconv_cf<<<gDwCf, 256, 0, stream>>>(A, wv_dw, wv_dwb, B);
  // attention + projection fold
  attn_m2<<<dim3(8, 64), 256, 0, stream>>>(G, SQ, SK, temp, dc, dl,
                                           dp_w1, dp_b1, dp_w2, dp_b2, prj_w, M2);
  // final GEMM: out[o][p] = sum_k M2[o][k] * Vt[p][k] + prj_b[o]
  gemm_mfma<2><<<gG, 256, 0, stream>>>(B, M2, prj_b, out);
}